// Round 13
// baseline (211.132 us; speedup 1.0000x reference)
//
#include <hip/hip_runtime.h>
#include <hip/hip_bf16.h>

#define NN 100000
#define NE 1600000
#define DD 128
#define NG 8

#define BSH 8              // 256-node buckets
#define KB 391             // ceil(NN / 256)
#define BMASK 255
#define PB 512             // phase-1/2 blocks
#define CHUNK 3125         // NE / PB exactly
#define SCAN_N (KB * PB)
#define GHB 98             // gid-histo blocks

typedef unsigned short u16;
typedef unsigned char u8;
typedef __attribute__((ext_vector_type(8))) short short8;
typedef __attribute__((ext_vector_type(4))) float f32x4;
typedef __attribute__((ext_vector_type(2))) float f32x2;

static __device__ __forceinline__ u16 f2bf(float f) {
  unsigned u = __float_as_uint(f);
  u += 0x7fffu + ((u >> 16) & 1);
  return (u16)(u >> 16);
}
static __device__ __forceinline__ u8 f2fp8(float f) {
  return (u8)(__builtin_amdgcn_cvt_pk_fp8_f32(f, f, 0, false) & 0xFF);
}

// ---- merged first launch: p1 histograms + W transposes + gid histo + pooled zero ----
__global__ __launch_bounds__(256) void p1x(const int* __restrict__ src,
                                           const int* __restrict__ dst,
                                           int* __restrict__ countsS,
                                           int* __restrict__ countsD,
                                           const float* __restrict__ W1,
                                           const float* __restrict__ W2,
                                           u16* __restrict__ Wt1,
                                           u16* __restrict__ Wt2,
                                           const int* __restrict__ gid,
                                           int* __restrict__ cnt_part,
                                           float* __restrict__ pooled) {
  __shared__ int hs[KB], hd[KB];
  __shared__ int h8[NG];
  int t = threadIdx.x, b = blockIdx.x;
  if (b < PB) {
    for (int i = t; i < KB; i += 256) { hs[i] = 0; hd[i] = 0; }
    __syncthreads();
    int e0 = b * CHUNK;
    for (int i = t; i < CHUNK; i += 256) {
      atomicAdd(&hs[src[e0 + i] >> BSH], 1);
      atomicAdd(&hd[dst[e0 + i] >> BSH], 1);
    }
    __syncthreads();
    for (int i = t; i < KB; i += 256) {
      countsS[i * PB + b] = hs[i];
      countsD[i * PB + b] = hd[i];
    }
  } else if (b < PB + 128) {
    int i = (b - PB) * 256 + t;  // 0..32767
    if (i < DD * DD) {
      int n = i >> 7, k = i & 127;
      Wt1[i] = f2bf(W1[k * DD + n]);
    } else {
      int i2 = i - DD * DD;
      int n = i2 >> 7, k = i2 & 127;
      Wt2[i2] = f2bf(W2[k * DD + n]);
    }
  } else if (b < PB + 128 + GHB) {
    int blk = b - PB - 128;
    if (t < NG) h8[t] = 0;
    __syncthreads();
    for (int i = blk * 256 + t; i < NN; i += GHB * 256)
      atomicAdd(&h8[gid[i]], 1);
    __syncthreads();
    if (t < NG) cnt_part[blk * NG + t] = h8[t];
  } else {
    for (int i = t; i < NG * DD; i += 256) pooled[i] = 0.f;
  }
}

// grid = 2*KB: per-bucket exclusive scan of its PB counts (in place), total out.
__global__ __launch_bounds__(256) void scanA(int* __restrict__ countsS,
                                             int* __restrict__ countsD,
                                             int* __restrict__ totS,
                                             int* __restrict__ totD) {
  __shared__ int data[PB];
  __shared__ int part[256];
  int b = blockIdx.x;
  int isS = (b < KB);
  int k = isS ? b : b - KB;
  int* counts = isS ? countsS : countsD;
  int* tot = isS ? totS : totD;
  int t = threadIdx.x;
  int* c = counts + (size_t)k * PB;
  data[t] = c[t];
  data[t + 256] = c[t + 256];
  __syncthreads();
  int a0 = data[2 * t], a1 = data[2 * t + 1];
  int s = a0 + a1;
  part[t] = s;
  __syncthreads();
  for (int off = 1; off < 256; off <<= 1) {
    int v = (t >= off) ? part[t - off] : 0;
    __syncthreads();
    part[t] += v;
    __syncthreads();
  }
  int ex = part[t] - s;
  data[2 * t] = ex;
  data[2 * t + 1] = ex + a0;
  __syncthreads();
  c[t] = data[t];
  c[t + 256] = data[t + 256];
  if (t == 255) tot[k] = part[255];
}

// combined scatter with in-block base scan (scanB folded in):
// recsD (u32 CSR records) + recsS (u8 src low bits); block 0 publishes base arrays.
__global__ __launch_bounds__(256) void p2x(const int* __restrict__ src,
                                           const int* __restrict__ dst,
                                           const int* __restrict__ countsS,
                                           const int* __restrict__ countsD,
                                           const int* __restrict__ totS,
                                           const int* __restrict__ totD,
                                           int* __restrict__ baseS,
                                           int* __restrict__ baseD,
                                           u8* __restrict__ recsS,
                                           unsigned* __restrict__ recsD) {
  __shared__ int data[512];
  __shared__ int part[256];
  __shared__ int bS[KB + 1], bD[KB + 1];
  __shared__ int curS[KB], curD[KB];
  int t = threadIdx.x, blk = blockIdx.x;
  // exclusive scan of totS -> bS, totD -> bD (each 391 entries, 512-slot scan)
#pragma unroll
  for (int pass = 0; pass < 2; ++pass) {
    const int* tot = pass ? totD : totS;
    int* bb = pass ? bD : bS;
    data[t] = (t < KB) ? tot[t] : 0;
    data[t + 256] = (t + 256 < KB) ? tot[t + 256] : 0;
    __syncthreads();
    int a0 = data[2 * t], a1 = data[2 * t + 1];
    int s = a0 + a1;
    part[t] = s;
    __syncthreads();
    for (int off = 1; off < 256; off <<= 1) {
      int v = (t >= off) ? part[t - off] : 0;
      __syncthreads();
      part[t] += v;
      __syncthreads();
    }
    int ex = part[t] - s;
    int i0 = 2 * t, i1 = 2 * t + 1;
    if (i0 <= KB) bb[i0] = ex;
    if (i1 <= KB) bb[i1] = ex + a0;
    __syncthreads();
  }
  for (int i = t; i < KB; i += 256) {
    curS[i] = countsS[i * PB + blk] + bS[i];
    curD[i] = countsD[i * PB + blk] + bD[i];
  }
  if (blk == 0) {
    for (int i = t; i <= KB; i += 256) {
      baseS[i] = bS[i];
      baseD[i] = bD[i];
    }
  }
  __syncthreads();
  int e0 = blk * CHUNK;
  for (int i = t; i < CHUNK; i += 256) {
    int s = src[e0 + i];
    int d = dst[e0 + i];
    int ps = atomicAdd(&curS[s >> BSH], 1);
    recsS[ps] = (u8)(s & BMASK);
    int pd = atomicAdd(&curD[d >> BSH], 1);
    recsD[pd] = (unsigned)s | ((unsigned)(d & BMASK) << 17);
  }
}

// merged grid 2*KB: blocks [0,KB) = src histogram -> rs_out AND x->fp8 scaled conv;
// blocks [KB,2KB) = dst: deg_in-free cursor_end + csr scatter + rs_in.
__global__ __launch_bounds__(256) void sd_p3x(const u8* __restrict__ recsS,
                                              const int* __restrict__ baseS,
                                              float* __restrict__ rs_out,
                                              const float* __restrict__ x,
                                              u8* __restrict__ bufA,
                                              const unsigned* __restrict__ recsD,
                                              const int* __restrict__ baseD,
                                              int* __restrict__ csr_src,
                                              int* __restrict__ cursor_end,
                                              int* __restrict__ deg_in,
                                              float* __restrict__ rs_in) {
  __shared__ int hist[256];
  __shared__ int part[256];
  __shared__ float rsl[256];
  int t = threadIdx.x;
  if (blockIdx.x < KB) {
    int k = blockIdx.x;
    int rbeg = baseS[k];
    int rend = baseS[k + 1];
    hist[t] = 0;
    __syncthreads();
    for (int i = rbeg + t; i < rend; i += 256) atomicAdd(&hist[recsS[i]], 1);
    __syncthreads();
    int nbase = k << BSH;
    int n = nbase + t;
    float rv = rsqrtf(fmaxf((float)hist[t], 1.f));
    rsl[t] = rv;
    if (n < NN) rs_out[n] = rv;
    __syncthreads();
    // fused conv: x[node] * rs -> fp8 row-major, 256 nodes x 16 chunks of 8
    for (int i = t; i < 256 * 16; i += 256) {
      int row = i >> 4, c = i & 15;
      int node = nbase + row;
      if (node >= NN) break;   // rows processed in order; tail bucket only
      float w = rsl[row];
      const float4* p = (const float4*)(x + (size_t)node * DD + c * 8);
      float4 a = p[0], b = p[1];
      int lo = 0, hi = 0;
      lo = __builtin_amdgcn_cvt_pk_fp8_f32(a.x * w, a.y * w, lo, false);
      lo = __builtin_amdgcn_cvt_pk_fp8_f32(a.z * w, a.w * w, lo, true);
      hi = __builtin_amdgcn_cvt_pk_fp8_f32(b.x * w, b.y * w, hi, false);
      hi = __builtin_amdgcn_cvt_pk_fp8_f32(b.z * w, b.w * w, hi, true);
      *(uint2*)(bufA + (size_t)node * DD + c * 8) = make_uint2((unsigned)lo, (unsigned)hi);
    }
  } else {
    int k = blockIdx.x - KB;
    int rbeg = baseD[k];
    int rend = baseD[k + 1];
    hist[t] = 0;
    __syncthreads();
    for (int i = rbeg + t; i < rend; i += 256) atomicAdd(&hist[recsD[i] >> 17], 1);
    __syncthreads();
    int h = hist[t];
    part[t] = h;
    __syncthreads();
    for (int off = 1; off < 256; off <<= 1) {
      int v = (t >= off) ? part[t - off] : 0;
      __syncthreads();
      part[t] += v;
      __syncthreads();
    }
    int run = rbeg + part[t] - h;   // exclusive
    int n = (k << BSH) + t;
    if (n < NN) {
      cursor_end[n] = run + h;
      deg_in[n] = h;
      rs_in[n] = rsqrtf(fmaxf((float)h, 1.f));
    }
    hist[t] = run;
    __syncthreads();
    for (int i = rbeg + t; i < rend; i += 256) {
      unsigned r = recsD[i];
      int pos = atomicAdd(&hist[r >> 17], 1);
      csr_src[pos] = (int)(r & 0x1FFFF);
    }
  }
}

// One 8-lane group per dst node; lane q covers fp8 elems 16q..16q+15 (16B).
// csr indices loaded as int4 (sequential), rows 8-deep in flight.
__global__ __launch_bounds__(256) void gather_agg_fp8(
    const uint4* __restrict__ Hv, const int* __restrict__ csr_src,
    const int* __restrict__ cursor_end, const int* __restrict__ deg_in,
    u16* __restrict__ agg) {
  int node = blockIdx.x * 32 + (threadIdx.x >> 3);
  if (node >= NN) return;
  int q = threadIdx.x & 7;
  int end = cursor_end[node];
  int j = end - deg_in[node];
  float acc[16];
#pragma unroll
  for (int i = 0; i < 16; ++i) acc[i] = 0.f;
#define ACCV(v) { f32x2 t_;                                                        \
  t_ = __builtin_amdgcn_cvt_pk_f32_fp8((int)(v).x, false); acc[0] += t_.x;  acc[1] += t_.y;  \
  t_ = __builtin_amdgcn_cvt_pk_f32_fp8((int)(v).x, true);  acc[2] += t_.x;  acc[3] += t_.y;  \
  t_ = __builtin_amdgcn_cvt_pk_f32_fp8((int)(v).y, false); acc[4] += t_.x;  acc[5] += t_.y;  \
  t_ = __builtin_amdgcn_cvt_pk_f32_fp8((int)(v).y, true);  acc[6] += t_.x;  acc[7] += t_.y;  \
  t_ = __builtin_amdgcn_cvt_pk_f32_fp8((int)(v).z, false); acc[8] += t_.x;  acc[9] += t_.y;  \
  t_ = __builtin_amdgcn_cvt_pk_f32_fp8((int)(v).z, true);  acc[10] += t_.x; acc[11] += t_.y; \
  t_ = __builtin_amdgcn_cvt_pk_f32_fp8((int)(v).w, false); acc[12] += t_.x; acc[13] += t_.y; \
  t_ = __builtin_amdgcn_cvt_pk_f32_fp8((int)(v).w, true);  acc[14] += t_.x; acc[15] += t_.y; }
  // scalar prologue to 16B-align the idx pointer
  for (; j < end && (j & 3); ++j) {
    uint4 v = Hv[(size_t)csr_src[j] * 8 + q];
    ACCV(v)
  }
  for (; j + 8 <= end; j += 8) {
    int4 sa = *(const int4*)(csr_src + j);
    int4 sb = *(const int4*)(csr_src + j + 4);
    uint4 v0 = Hv[(size_t)sa.x * 8 + q];
    uint4 v1 = Hv[(size_t)sa.y * 8 + q];
    uint4 v2 = Hv[(size_t)sa.z * 8 + q];
    uint4 v3 = Hv[(size_t)sa.w * 8 + q];
    uint4 v4 = Hv[(size_t)sb.x * 8 + q];
    uint4 v5 = Hv[(size_t)sb.y * 8 + q];
    uint4 v6 = Hv[(size_t)sb.z * 8 + q];
    uint4 v7 = Hv[(size_t)sb.w * 8 + q];
    ACCV(v0) ACCV(v1) ACCV(v2) ACCV(v3) ACCV(v4) ACCV(v5) ACCV(v6) ACCV(v7)
  }
  if (j + 4 <= end) {
    int4 sa = *(const int4*)(csr_src + j);
    uint4 v0 = Hv[(size_t)sa.x * 8 + q];
    uint4 v1 = Hv[(size_t)sa.y * 8 + q];
    uint4 v2 = Hv[(size_t)sa.z * 8 + q];
    uint4 v3 = Hv[(size_t)sa.w * 8 + q];
    ACCV(v0) ACCV(v1) ACCV(v2) ACCV(v3)
    j += 4;
  }
  for (; j < end; ++j) {
    uint4 v = Hv[(size_t)csr_src[j] * 8 + q];
    ACCV(v)
  }
#undef ACCV
  uint4 o0, o1;
  o0.x = (unsigned)f2bf(acc[0])  | ((unsigned)f2bf(acc[1])  << 16);
  o0.y = (unsigned)f2bf(acc[2])  | ((unsigned)f2bf(acc[3])  << 16);
  o0.z = (unsigned)f2bf(acc[4])  | ((unsigned)f2bf(acc[5])  << 16);
  o0.w = (unsigned)f2bf(acc[6])  | ((unsigned)f2bf(acc[7])  << 16);
  o1.x = (unsigned)f2bf(acc[8])  | ((unsigned)f2bf(acc[9])  << 16);
  o1.y = (unsigned)f2bf(acc[10]) | ((unsigned)f2bf(acc[11]) << 16);
  o1.z = (unsigned)f2bf(acc[12]) | ((unsigned)f2bf(acc[13]) << 16);
  o1.w = (unsigned)f2bf(acc[14]) | ((unsigned)f2bf(acc[15]) << 16);
  u16* op = agg + (size_t)node * DD + q * 16;
  *(uint4*)op = o0;
  *(uint4*)(op + 8) = o1;
}

// ---- LDS-staged GEMM core ----
#define GEMM_PRE                                                              \
  __shared__ uint4 Wl4[2048]; /* 32 KB */                                     \
  int tid = threadIdx.x;                                                      \
  {                                                                           \
    const uint4* Wg4 = (const uint4*)Wt;                                      \
    for (int i = tid; i < 2048; i += 256) {                                   \
      int row = i >> 4, c = i & 15;                                           \
      Wl4[(row << 4) | (c ^ (row & 15))] = Wg4[i];                            \
    }                                                                         \
  }                                                                           \
  int wid = tid >> 6;                                                         \
  int lane = tid & 63;                                                        \
  int l15 = lane & 15;                                                        \
  int kg = lane >> 4;                                                         \
  int rowbase = blockIdx.x * 128 + wid * 32;                                  \
  f32x4 acc[2][8];                                                            \
  short8 a[2][4];                                                             \
  _Pragma("unroll")                                                           \
  for (int t = 0; t < 2; ++t) {                                               \
    int arow = rowbase + t * 16 + l15;                                        \
    bool ok = arow < NN;                                                      \
    const u16* aptr = Ab + (size_t)arow * DD + kg * 8;                        \
    _Pragma("unroll")                                                         \
    for (int kt = 0; kt < 4; ++kt) {                                          \
      a[t][kt] = ok ? *(const short8*)(aptr + kt * 32)                        \
                    : (short8){0, 0, 0, 0, 0, 0, 0, 0};                       \
      acc[0][kt] = (f32x4){0.f, 0.f, 0.f, 0.f};                               \
      acc[0][kt + 4] = (f32x4){0.f, 0.f, 0.f, 0.f};                           \
      acc[1][kt] = (f32x4){0.f, 0.f, 0.f, 0.f};                               \
      acc[1][kt + 4] = (f32x4){0.f, 0.f, 0.f, 0.f};                           \
    }                                                                         \
  }                                                                           \
  __syncthreads();                                                            \
  _Pragma("unroll")                                                           \
  for (int n = 0; n < 8; ++n) {                                               \
    _Pragma("unroll")                                                         \
    for (int kt = 0; kt < 4; ++kt) {                                          \
      short8 b = *(const short8*)(Wl4 + (((n * 16 + l15) << 4) |              \
                                         ((kg + kt * 4) ^ l15)));             \
      acc[0][n] = __builtin_amdgcn_mfma_f32_16x16x32_bf16(a[0][kt], b, acc[0][n], 0, 0, 0); \
      acc[1][n] = __builtin_amdgcn_mfma_f32_16x16x32_bf16(a[1][kt], b, acc[1][n], 0, 0, 0); \
    }                                                                         \
  }

// C = fp8( relu((A@W)*rs + bias) * post ), row-major byte out.
__global__ __launch_bounds__(256) void gemm_mfma_fp8out(
    const u16* __restrict__ Ab, const u16* __restrict__ Wt,
    const float* __restrict__ bias, const float* __restrict__ rs,
    const float* __restrict__ post, u8* __restrict__ Cb) {
  GEMM_PRE
#pragma unroll
  for (int t = 0; t < 2; ++t) {
    int crow0 = rowbase + t * 16 + kg * 4;
#pragma unroll
    for (int j = 0; j < 4; ++j) {
      int r = crow0 + j;
      if (r < NN) {
        float s = rs[r];
        float ps = post[r];
#pragma unroll
        for (int n = 0; n < 8; ++n) {
          float v = fmaxf(acc[t][n][j] * s + bias[n * 16 + l15], 0.f) * ps;
          Cb[(size_t)r * DD + n * 16 + l15] = f2fp8(v);
        }
      }
    }
  }
}

// Layer-2 GEMM with pooling fused into the epilogue: no feature output.
__global__ __launch_bounds__(256) void gemm_mfma_pool(
    const u16* __restrict__ Ab, const u16* __restrict__ Wt,
    const float* __restrict__ bias, const float* __restrict__ rs,
    const int* __restrict__ gid, float* __restrict__ pooled) {
  __shared__ float pl[NG * DD];  // 4 KB
  for (int i = threadIdx.x; i < NG * DD; i += 256) pl[i] = 0.f;
  GEMM_PRE
  float pacc[8];
#pragma unroll
  for (int n = 0; n < 8; ++n) pacc[n] = 0.f;
  int curg = -1;
#pragma unroll
  for (int t = 0; t < 2; ++t) {
    int crow0 = rowbase + t * 16 + kg * 4;
#pragma unroll
    for (int j = 0; j < 4; ++j) {
      int r = crow0 + j;
      if (r < NN) {
        int g = gid[r];
        if (g != curg) {
          if (curg >= 0) {
#pragma unroll
            for (int n = 0; n < 8; ++n) {
              atomicAdd(&pl[curg * DD + n * 16 + l15], pacc[n]);
              pacc[n] = 0.f;
            }
          }
          curg = g;
        }
        float s = rs[r];
#pragma unroll
        for (int n = 0; n < 8; ++n)
          pacc[n] += fmaxf(acc[t][n][j] * s + bias[n * 16 + l15], 0.f);
      }
    }
  }
  if (curg >= 0) {
#pragma unroll
    for (int n = 0; n < 8; ++n)
      atomicAdd(&pl[curg * DD + n * 16 + l15], pacc[n]);
  }
  __syncthreads();
  int rlo = blockIdx.x * 128;
  int rhi = rlo + 127;
  if (rhi >= NN) rhi = NN - 1;
  int gmin = gid[rlo];
  int gmax = gid[rhi];
  int span = (gmax - gmin + 1) * DD;
  for (int i = tid; i < span; i += 256) {
    float v = pl[gmin * DD + i];
    if (v != 0.f) atomicAdd(&pooled[gmin * DD + i], v);
  }
}

__global__ __launch_bounds__(128) void final_kernel(const float* __restrict__ pooled,
                                                    const int* __restrict__ cnt_part,
                                                    const float* __restrict__ prelu_a,
                                                    const float* __restrict__ linW,
                                                    const float* __restrict__ linb,
                                                    float* __restrict__ out) {
  int t = threadIdx.x;  // 128
  __shared__ float red[2];
  __shared__ int cntl[NG];
  if (t < NG) {
    int s = 0;
    for (int b = 0; b < GHB; ++b) s += cnt_part[b * NG + t];
    cntl[t] = s;
  }
  __syncthreads();
  float w = linW[t];
  float alpha = prelu_a[0];
  float lb = linb[0];
  for (int g = 0; g < NG; ++g) {
    float v = pooled[g * DD + t] / fmaxf((float)cntl[g], 1.f);
    v = v > 0.f ? v : alpha * v;
    float p = v * w;
#pragma unroll
    for (int off = 32; off >= 1; off >>= 1) p += __shfl_down(p, off, 64);
    if ((t & 63) == 0) red[t >> 6] = p;
    __syncthreads();
    if (t == 0) {
      float s = red[0] + red[1] + lb;
      out[g] = 1.f / (1.f + expf(-s));
    }
    __syncthreads();
  }
}

extern "C" void kernel_launch(void* const* d_in, const int* in_sizes, int n_in,
                              void* d_out, int out_size, void* d_ws, size_t ws_size,
                              hipStream_t stream) {
  const float* x   = (const float*)d_in[0];
  const int*   src = (const int*)d_in[1];
  const int*   dst = (const int*)d_in[2];
  const int*   gid = (const int*)d_in[3];
  const float* W1  = (const float*)d_in[4];
  const float* b1  = (const float*)d_in[5];
  const float* W2  = (const float*)d_in[6];
  const float* b2  = (const float*)d_in[7];
  const float* pa  = (const float*)d_in[8];
  const float* lW  = (const float*)d_in[9];
  const float* lb  = (const float*)d_in[10];
  float* out = (float*)d_out;

  char* ws = (char*)d_ws;
  size_t o = 0;
  auto alloc = [&](size_t bytes) {
    size_t r = o;
    o += (bytes + 255) & ~(size_t)255;
    return r;
  };
  int*   deg_in  = (int*)(ws + alloc((size_t)NN * 4));
  float* rs_out  = (float*)(ws + alloc((size_t)NN * 4));
  float* rs_in   = (float*)(ws + alloc((size_t)NN * 4));
  int*   countsS = (int*)(ws + alloc((size_t)SCAN_N * 4));
  int*   countsD = (int*)(ws + alloc((size_t)SCAN_N * 4));
  int*   totS    = (int*)(ws + alloc((size_t)KB * 4));
  int*   totD    = (int*)(ws + alloc((size_t)KB * 4));
  int*   baseS   = (int*)(ws + alloc((size_t)(KB + 1) * 4));
  int*   baseD   = (int*)(ws + alloc((size_t)(KB + 1) * 4));
  int*   cursor_end = (int*)(ws + alloc((size_t)NN * 4));
  u8*    recsS   = (u8*)(ws + alloc((size_t)NE));
  unsigned* recsD = (unsigned*)(ws + alloc((size_t)NE * 4));
  int*   csr_src = (int*)(ws + alloc((size_t)NE * 4));
  u16*   Wt1     = (u16*)(ws + alloc((size_t)DD * DD * 2));
  u16*   Wt2     = (u16*)(ws + alloc((size_t)DD * DD * 2));
  u8*    bufA    = (u8*)(ws + alloc((size_t)NN * DD));      // fp8 row-major L1 input
  u8*    bufB    = (u8*)(ws + alloc((size_t)NN * DD));      // fp8 row-major L2 input
  u16*   aggbuf  = (u16*)(ws + alloc((size_t)NN * DD * 2)); // bf16 row-major agg
  float* pooled  = (float*)(ws + alloc((size_t)NG * DD * 4));
  int*   cnt_part = (int*)(ws + alloc((size_t)GHB * NG * 4));

  // 1: p1 bucket histos + W transposes + gid histo partials + pooled zero
  p1x<<<PB + 128 + GHB + 1, 256, 0, stream>>>(src, dst, countsS, countsD,
                                              W1, W2, Wt1, Wt2, gid, cnt_part, pooled);
  // 2: per-bucket scans
  scanA<<<2 * KB, 256, 0, stream>>>(countsS, countsD, totS, totD);
  // 3: record scatter (+ in-block base scan, publishes baseS/baseD)
  p2x<<<PB, 256, 0, stream>>>(src, dst, countsS, countsD, totS, totD,
                              baseS, baseD, recsS, recsD);
  // 4: src finalize (rs_out + fused x->fp8 conv) ∥ dst finalize (CSR)
  sd_p3x<<<2 * KB, 256, 0, stream>>>(recsS, baseS, rs_out, x, bufA,
                                     recsD, baseD, csr_src, cursor_end, deg_in, rs_in);

  const int gablocks = (NN + 31) / 32;   // 3125
  const int gmblocks = (NN + 127) / 128; // 782

  // 5-6: layer 1
  gather_agg_fp8<<<gablocks, 256, 0, stream>>>((const uint4*)bufA, csr_src, cursor_end, deg_in, aggbuf);
  gemm_mfma_fp8out<<<gmblocks, 256, 0, stream>>>(aggbuf, Wt1, b1, rs_in, rs_out, bufB);
  // 7-8: layer 2
  gather_agg_fp8<<<gablocks, 256, 0, stream>>>((const uint4*)bufB, csr_src, cursor_end, deg_in, aggbuf);
  gemm_mfma_pool<<<gmblocks, 256, 0, stream>>>(aggbuf, Wt2, b2, rs_in, gid, pooled);
  // 9: head
  final_kernel<<<1, 128, 0, stream>>>(pooled, cnt_part, pa, lW, lb, out);
}

// Round 14
// 193.001 us; speedup vs baseline: 1.0939x; 1.0939x over previous
//
#include <hip/hip_runtime.h>
#include <hip/hip_bf16.h>

#define NN 100000
#define NE 1600000
#define DD 128
#define NG 8

#define BSH 8              // 256-node buckets
#define KB 391             // ceil(NN / 256)
#define BMASK 255
#define PB 512             // phase-1/2 blocks
#define CHUNK 3125         // NE / PB exactly
#define SCAN_N (KB * PB)
#define GHB 98             // gid-histo blocks

typedef unsigned short u16;
typedef unsigned char u8;
typedef __attribute__((ext_vector_type(8))) short short8;
typedef __attribute__((ext_vector_type(4))) float f32x4;
typedef __attribute__((ext_vector_type(2))) float f32x2;

static __device__ __forceinline__ u16 f2bf(float f) {
  unsigned u = __float_as_uint(f);
  u += 0x7fffu + ((u >> 16) & 1);
  return (u16)(u >> 16);
}
static __device__ __forceinline__ u8 f2fp8(float f) {
  return (u8)(__builtin_amdgcn_cvt_pk_fp8_f32(f, f, 0, false) & 0xFF);
}

// ---- merged first launch: p1 histograms + W transposes + gid histo + pooled zero ----
__global__ __launch_bounds__(256) void p1x(const int* __restrict__ src,
                                           const int* __restrict__ dst,
                                           int* __restrict__ countsS,
                                           int* __restrict__ countsD,
                                           const float* __restrict__ W1,
                                           const float* __restrict__ W2,
                                           u16* __restrict__ Wt1,
                                           u16* __restrict__ Wt2,
                                           const int* __restrict__ gid,
                                           int* __restrict__ cnt_part,
                                           float* __restrict__ pooled) {
  __shared__ int hs[KB], hd[KB];
  __shared__ int h8[NG];
  int t = threadIdx.x, b = blockIdx.x;
  if (b < PB) {
    for (int i = t; i < KB; i += 256) { hs[i] = 0; hd[i] = 0; }
    __syncthreads();
    int e0 = b * CHUNK;
    for (int i = t; i < CHUNK; i += 256) {
      atomicAdd(&hs[src[e0 + i] >> BSH], 1);
      atomicAdd(&hd[dst[e0 + i] >> BSH], 1);
    }
    __syncthreads();
    for (int i = t; i < KB; i += 256) {
      countsS[i * PB + b] = hs[i];
      countsD[i * PB + b] = hd[i];
    }
  } else if (b < PB + 128) {
    int i = (b - PB) * 256 + t;  // 0..32767
    if (i < DD * DD) {
      int n = i >> 7, k = i & 127;
      Wt1[i] = f2bf(W1[k * DD + n]);
    } else {
      int i2 = i - DD * DD;
      int n = i2 >> 7, k = i2 & 127;
      Wt2[i2] = f2bf(W2[k * DD + n]);
    }
  } else if (b < PB + 128 + GHB) {
    int blk = b - PB - 128;
    if (t < NG) h8[t] = 0;
    __syncthreads();
    for (int i = blk * 256 + t; i < NN; i += GHB * 256)
      atomicAdd(&h8[gid[i]], 1);
    __syncthreads();
    if (t < NG) cnt_part[blk * NG + t] = h8[t];
  } else {
    for (int i = t; i < NG * DD; i += 256) pooled[i] = 0.f;
  }
}

// grid = 2*KB: per-bucket exclusive scan of its PB counts (in place), total out.
__global__ __launch_bounds__(256) void scanA(int* __restrict__ countsS,
                                             int* __restrict__ countsD,
                                             int* __restrict__ totS,
                                             int* __restrict__ totD) {
  __shared__ int data[PB];
  __shared__ int part[256];
  int b = blockIdx.x;
  int isS = (b < KB);
  int k = isS ? b : b - KB;
  int* counts = isS ? countsS : countsD;
  int* tot = isS ? totS : totD;
  int t = threadIdx.x;
  int* c = counts + (size_t)k * PB;
  data[t] = c[t];
  data[t + 256] = c[t + 256];
  __syncthreads();
  int a0 = data[2 * t], a1 = data[2 * t + 1];
  int s = a0 + a1;
  part[t] = s;
  __syncthreads();
  for (int off = 1; off < 256; off <<= 1) {
    int v = (t >= off) ? part[t - off] : 0;
    __syncthreads();
    part[t] += v;
    __syncthreads();
  }
  int ex = part[t] - s;
  data[2 * t] = ex;
  data[2 * t + 1] = ex + a0;
  __syncthreads();
  c[t] = data[t];
  c[t + 256] = data[t + 256];
  if (t == 255) tot[k] = part[255];
}

// combined scatter with in-block base scan (scanB folded in):
// recsD (u32 CSR records) + recsS (u8 src low bits); block 0 publishes base arrays.
__global__ __launch_bounds__(256) void p2x(const int* __restrict__ src,
                                           const int* __restrict__ dst,
                                           const int* __restrict__ countsS,
                                           const int* __restrict__ countsD,
                                           const int* __restrict__ totS,
                                           const int* __restrict__ totD,
                                           int* __restrict__ baseS,
                                           int* __restrict__ baseD,
                                           u8* __restrict__ recsS,
                                           unsigned* __restrict__ recsD) {
  __shared__ int data[512];
  __shared__ int part[256];
  __shared__ int bS[KB + 1], bD[KB + 1];
  __shared__ int curS[KB], curD[KB];
  int t = threadIdx.x, blk = blockIdx.x;
  // exclusive scan of totS -> bS, totD -> bD (each 391 entries, 512-slot scan)
#pragma unroll
  for (int pass = 0; pass < 2; ++pass) {
    const int* tot = pass ? totD : totS;
    int* bb = pass ? bD : bS;
    data[t] = (t < KB) ? tot[t] : 0;
    data[t + 256] = (t + 256 < KB) ? tot[t + 256] : 0;
    __syncthreads();
    int a0 = data[2 * t], a1 = data[2 * t + 1];
    int s = a0 + a1;
    part[t] = s;
    __syncthreads();
    for (int off = 1; off < 256; off <<= 1) {
      int v = (t >= off) ? part[t - off] : 0;
      __syncthreads();
      part[t] += v;
      __syncthreads();
    }
    int ex = part[t] - s;
    int i0 = 2 * t, i1 = 2 * t + 1;
    if (i0 <= KB) bb[i0] = ex;
    if (i1 <= KB) bb[i1] = ex + a0;
    __syncthreads();
  }
  for (int i = t; i < KB; i += 256) {
    curS[i] = countsS[i * PB + blk] + bS[i];
    curD[i] = countsD[i * PB + blk] + bD[i];
  }
  if (blk == 0) {
    for (int i = t; i <= KB; i += 256) {
      baseS[i] = bS[i];
      baseD[i] = bD[i];
    }
  }
  __syncthreads();
  int e0 = blk * CHUNK;
  for (int i = t; i < CHUNK; i += 256) {
    int s = src[e0 + i];
    int d = dst[e0 + i];
    int ps = atomicAdd(&curS[s >> BSH], 1);
    recsS[ps] = (u8)(s & BMASK);
    int pd = atomicAdd(&curD[d >> BSH], 1);
    recsD[pd] = (unsigned)s | ((unsigned)(d & BMASK) << 17);
  }
}

// merged grid 2*KB: blocks [0,KB) = src histogram -> rs_out AND x->fp8 scaled conv;
// blocks [KB,2KB) = dst: cursor_end + csr scatter + deg_in/rs_in.
__global__ __launch_bounds__(256) void sd_p3x(const u8* __restrict__ recsS,
                                              const int* __restrict__ baseS,
                                              float* __restrict__ rs_out,
                                              const float* __restrict__ x,
                                              u8* __restrict__ bufA,
                                              const unsigned* __restrict__ recsD,
                                              const int* __restrict__ baseD,
                                              int* __restrict__ csr_src,
                                              int* __restrict__ cursor_end,
                                              int* __restrict__ deg_in,
                                              float* __restrict__ rs_in) {
  __shared__ int hist[256];
  __shared__ int part[256];
  __shared__ float rsl[256];
  int t = threadIdx.x;
  if (blockIdx.x < KB) {
    int k = blockIdx.x;
    int rbeg = baseS[k];
    int rend = baseS[k + 1];
    hist[t] = 0;
    __syncthreads();
    for (int i = rbeg + t; i < rend; i += 256) atomicAdd(&hist[recsS[i]], 1);
    __syncthreads();
    int nbase = k << BSH;
    int n = nbase + t;
    float rv = rsqrtf(fmaxf((float)hist[t], 1.f));
    rsl[t] = rv;
    if (n < NN) rs_out[n] = rv;
    __syncthreads();
    // fused conv: x[node] * rs -> fp8 row-major, 256 nodes x 16 chunks of 8
    for (int i = t; i < 256 * 16; i += 256) {
      int row = i >> 4, c = i & 15;
      int node = nbase + row;
      if (node >= NN) break;   // rows processed in order; tail bucket only
      float w = rsl[row];
      const float4* p = (const float4*)(x + (size_t)node * DD + c * 8);
      float4 a = p[0], b = p[1];
      int lo = 0, hi = 0;
      lo = __builtin_amdgcn_cvt_pk_fp8_f32(a.x * w, a.y * w, lo, false);
      lo = __builtin_amdgcn_cvt_pk_fp8_f32(a.z * w, a.w * w, lo, true);
      hi = __builtin_amdgcn_cvt_pk_fp8_f32(b.x * w, b.y * w, hi, false);
      hi = __builtin_amdgcn_cvt_pk_fp8_f32(b.z * w, b.w * w, hi, true);
      *(uint2*)(bufA + (size_t)node * DD + c * 8) = make_uint2((unsigned)lo, (unsigned)hi);
    }
  } else {
    int k = blockIdx.x - KB;
    int rbeg = baseD[k];
    int rend = baseD[k + 1];
    hist[t] = 0;
    __syncthreads();
    for (int i = rbeg + t; i < rend; i += 256) atomicAdd(&hist[recsD[i] >> 17], 1);
    __syncthreads();
    int h = hist[t];
    part[t] = h;
    __syncthreads();
    for (int off = 1; off < 256; off <<= 1) {
      int v = (t >= off) ? part[t - off] : 0;
      __syncthreads();
      part[t] += v;
      __syncthreads();
    }
    int run = rbeg + part[t] - h;   // exclusive
    int n = (k << BSH) + t;
    if (n < NN) {
      cursor_end[n] = run + h;
      deg_in[n] = h;
      rs_in[n] = rsqrtf(fmaxf((float)h, 1.f));
    }
    hist[t] = run;
    __syncthreads();
    for (int i = rbeg + t; i < rend; i += 256) {
      unsigned r = recsD[i];
      int pos = atomicAdd(&hist[r >> 17], 1);
      csr_src[pos] = (int)(r & 0x1FFFF);
    }
  }
}

// One 8-lane group per dst node; lane q covers fp8 elems 16q..16q+15 (16B).
// Round-12 form: 4-deep unroll, scalar idx loads — VGPR 44, occupancy ~44%.
__global__ __launch_bounds__(256) void gather_agg_fp8(
    const uint4* __restrict__ Hv, const int* __restrict__ csr_src,
    const int* __restrict__ cursor_end, const int* __restrict__ deg_in,
    u16* __restrict__ agg) {
  int node = blockIdx.x * 32 + (threadIdx.x >> 3);
  if (node >= NN) return;
  int q = threadIdx.x & 7;
  int end = cursor_end[node];
  int j = end - deg_in[node];
  float acc[16];
#pragma unroll
  for (int i = 0; i < 16; ++i) acc[i] = 0.f;
#define ACCV(v) { f32x2 t_;                                                        \
  t_ = __builtin_amdgcn_cvt_pk_f32_fp8((int)(v).x, false); acc[0] += t_.x;  acc[1] += t_.y;  \
  t_ = __builtin_amdgcn_cvt_pk_f32_fp8((int)(v).x, true);  acc[2] += t_.x;  acc[3] += t_.y;  \
  t_ = __builtin_amdgcn_cvt_pk_f32_fp8((int)(v).y, false); acc[4] += t_.x;  acc[5] += t_.y;  \
  t_ = __builtin_amdgcn_cvt_pk_f32_fp8((int)(v).y, true);  acc[6] += t_.x;  acc[7] += t_.y;  \
  t_ = __builtin_amdgcn_cvt_pk_f32_fp8((int)(v).z, false); acc[8] += t_.x;  acc[9] += t_.y;  \
  t_ = __builtin_amdgcn_cvt_pk_f32_fp8((int)(v).z, true);  acc[10] += t_.x; acc[11] += t_.y; \
  t_ = __builtin_amdgcn_cvt_pk_f32_fp8((int)(v).w, false); acc[12] += t_.x; acc[13] += t_.y; \
  t_ = __builtin_amdgcn_cvt_pk_f32_fp8((int)(v).w, true);  acc[14] += t_.x; acc[15] += t_.y; }
  for (; j + 4 <= end; j += 4) {
    int s0 = csr_src[j + 0];
    int s1 = csr_src[j + 1];
    int s2 = csr_src[j + 2];
    int s3 = csr_src[j + 3];
    uint4 v0 = Hv[(size_t)s0 * 8 + q];
    uint4 v1 = Hv[(size_t)s1 * 8 + q];
    uint4 v2 = Hv[(size_t)s2 * 8 + q];
    uint4 v3 = Hv[(size_t)s3 * 8 + q];
    ACCV(v0) ACCV(v1) ACCV(v2) ACCV(v3)
  }
  for (; j < end; ++j) {
    uint4 v = Hv[(size_t)csr_src[j] * 8 + q];
    ACCV(v)
  }
#undef ACCV
  uint4 o0, o1;
  o0.x = (unsigned)f2bf(acc[0])  | ((unsigned)f2bf(acc[1])  << 16);
  o0.y = (unsigned)f2bf(acc[2])  | ((unsigned)f2bf(acc[3])  << 16);
  o0.z = (unsigned)f2bf(acc[4])  | ((unsigned)f2bf(acc[5])  << 16);
  o0.w = (unsigned)f2bf(acc[6])  | ((unsigned)f2bf(acc[7])  << 16);
  o1.x = (unsigned)f2bf(acc[8])  | ((unsigned)f2bf(acc[9])  << 16);
  o1.y = (unsigned)f2bf(acc[10]) | ((unsigned)f2bf(acc[11]) << 16);
  o1.z = (unsigned)f2bf(acc[12]) | ((unsigned)f2bf(acc[13]) << 16);
  o1.w = (unsigned)f2bf(acc[14]) | ((unsigned)f2bf(acc[15]) << 16);
  u16* op = agg + (size_t)node * DD + q * 16;
  *(uint4*)op = o0;
  *(uint4*)(op + 8) = o1;
}

// ---- LDS-staged GEMM core ----
#define GEMM_PRE                                                              \
  __shared__ uint4 Wl4[2048]; /* 32 KB */                                     \
  int tid = threadIdx.x;                                                      \
  {                                                                           \
    const uint4* Wg4 = (const uint4*)Wt;                                      \
    for (int i = tid; i < 2048; i += 256) {                                   \
      int row = i >> 4, c = i & 15;                                           \
      Wl4[(row << 4) | (c ^ (row & 15))] = Wg4[i];                            \
    }                                                                         \
  }                                                                           \
  int wid = tid >> 6;                                                         \
  int lane = tid & 63;                                                        \
  int l15 = lane & 15;                                                        \
  int kg = lane >> 4;                                                         \
  int rowbase = blockIdx.x * 128 + wid * 32;                                  \
  f32x4 acc[2][8];                                                            \
  short8 a[2][4];                                                             \
  _Pragma("unroll")                                                           \
  for (int t = 0; t < 2; ++t) {                                               \
    int arow = rowbase + t * 16 + l15;                                        \
    bool ok = arow < NN;                                                      \
    const u16* aptr = Ab + (size_t)arow * DD + kg * 8;                        \
    _Pragma("unroll")                                                         \
    for (int kt = 0; kt < 4; ++kt) {                                          \
      a[t][kt] = ok ? *(const short8*)(aptr + kt * 32)                        \
                    : (short8){0, 0, 0, 0, 0, 0, 0, 0};                       \
      acc[0][kt] = (f32x4){0.f, 0.f, 0.f, 0.f};                               \
      acc[0][kt + 4] = (f32x4){0.f, 0.f, 0.f, 0.f};                           \
      acc[1][kt] = (f32x4){0.f, 0.f, 0.f, 0.f};                               \
      acc[1][kt + 4] = (f32x4){0.f, 0.f, 0.f, 0.f};                           \
    }                                                                         \
  }                                                                           \
  __syncthreads();                                                            \
  _Pragma("unroll")                                                           \
  for (int n = 0; n < 8; ++n) {                                               \
    _Pragma("unroll")                                                         \
    for (int kt = 0; kt < 4; ++kt) {                                          \
      short8 b = *(const short8*)(Wl4 + (((n * 16 + l15) << 4) |              \
                                         ((kg + kt * 4) ^ l15)));             \
      acc[0][n] = __builtin_amdgcn_mfma_f32_16x16x32_bf16(a[0][kt], b, acc[0][n], 0, 0, 0); \
      acc[1][n] = __builtin_amdgcn_mfma_f32_16x16x32_bf16(a[1][kt], b, acc[1][n], 0, 0, 0); \
    }                                                                         \
  }

// C = fp8( relu((A@W)*rs + bias) * post ), row-major byte out.
__global__ __launch_bounds__(256) void gemm_mfma_fp8out(
    const u16* __restrict__ Ab, const u16* __restrict__ Wt,
    const float* __restrict__ bias, const float* __restrict__ rs,
    const float* __restrict__ post, u8* __restrict__ Cb) {
  GEMM_PRE
#pragma unroll
  for (int t = 0; t < 2; ++t) {
    int crow0 = rowbase + t * 16 + kg * 4;
#pragma unroll
    for (int j = 0; j < 4; ++j) {
      int r = crow0 + j;
      if (r < NN) {
        float s = rs[r];
        float ps = post[r];
#pragma unroll
        for (int n = 0; n < 8; ++n) {
          float v = fmaxf(acc[t][n][j] * s + bias[n * 16 + l15], 0.f) * ps;
          Cb[(size_t)r * DD + n * 16 + l15] = f2fp8(v);
        }
      }
    }
  }
}

// Layer-2 GEMM with pooling fused into the epilogue: no feature output.
__global__ __launch_bounds__(256) void gemm_mfma_pool(
    const u16* __restrict__ Ab, const u16* __restrict__ Wt,
    const float* __restrict__ bias, const float* __restrict__ rs,
    const int* __restrict__ gid, float* __restrict__ pooled) {
  __shared__ float pl[NG * DD];  // 4 KB
  for (int i = threadIdx.x; i < NG * DD; i += 256) pl[i] = 0.f;
  GEMM_PRE
  float pacc[8];
#pragma unroll
  for (int n = 0; n < 8; ++n) pacc[n] = 0.f;
  int curg = -1;
#pragma unroll
  for (int t = 0; t < 2; ++t) {
    int crow0 = rowbase + t * 16 + kg * 4;
#pragma unroll
    for (int j = 0; j < 4; ++j) {
      int r = crow0 + j;
      if (r < NN) {
        int g = gid[r];
        if (g != curg) {
          if (curg >= 0) {
#pragma unroll
            for (int n = 0; n < 8; ++n) {
              atomicAdd(&pl[curg * DD + n * 16 + l15], pacc[n]);
              pacc[n] = 0.f;
            }
          }
          curg = g;
        }
        float s = rs[r];
#pragma unroll
        for (int n = 0; n < 8; ++n)
          pacc[n] += fmaxf(acc[t][n][j] * s + bias[n * 16 + l15], 0.f);
      }
    }
  }
  if (curg >= 0) {
#pragma unroll
    for (int n = 0; n < 8; ++n)
      atomicAdd(&pl[curg * DD + n * 16 + l15], pacc[n]);
  }
  __syncthreads();
  int rlo = blockIdx.x * 128;
  int rhi = rlo + 127;
  if (rhi >= NN) rhi = NN - 1;
  int gmin = gid[rlo];
  int gmax = gid[rhi];
  int span = (gmax - gmin + 1) * DD;
  for (int i = tid; i < span; i += 256) {
    float v = pl[gmin * DD + i];
    if (v != 0.f) atomicAdd(&pooled[gmin * DD + i], v);
  }
}

__global__ __launch_bounds__(128) void final_kernel(const float* __restrict__ pooled,
                                                    const int* __restrict__ cnt_part,
                                                    const float* __restrict__ prelu_a,
                                                    const float* __restrict__ linW,
                                                    const float* __restrict__ linb,
                                                    float* __restrict__ out) {
  int t = threadIdx.x;  // 128
  __shared__ float red[2];
  __shared__ int cntl[NG];
  if (t < NG) {
    int s = 0;
    for (int b = 0; b < GHB; ++b) s += cnt_part[b * NG + t];
    cntl[t] = s;
  }
  __syncthreads();
  float w = linW[t];
  float alpha = prelu_a[0];
  float lb = linb[0];
  for (int g = 0; g < NG; ++g) {
    float v = pooled[g * DD + t] / fmaxf((float)cntl[g], 1.f);
    v = v > 0.f ? v : alpha * v;
    float p = v * w;
#pragma unroll
    for (int off = 32; off >= 1; off >>= 1) p += __shfl_down(p, off, 64);
    if ((t & 63) == 0) red[t >> 6] = p;
    __syncthreads();
    if (t == 0) {
      float s = red[0] + red[1] + lb;
      out[g] = 1.f / (1.f + expf(-s));
    }
    __syncthreads();
  }
}

extern "C" void kernel_launch(void* const* d_in, const int* in_sizes, int n_in,
                              void* d_out, int out_size, void* d_ws, size_t ws_size,
                              hipStream_t stream) {
  const float* x   = (const float*)d_in[0];
  const int*   src = (const int*)d_in[1];
  const int*   dst = (const int*)d_in[2];
  const int*   gid = (const int*)d_in[3];
  const float* W1  = (const float*)d_in[4];
  const float* b1  = (const float*)d_in[5];
  const float* W2  = (const float*)d_in[6];
  const float* b2  = (const float*)d_in[7];
  const float* pa  = (const float*)d_in[8];
  const float* lW  = (const float*)d_in[9];
  const float* lb  = (const float*)d_in[10];
  float* out = (float*)d_out;

  char* ws = (char*)d_ws;
  size_t o = 0;
  auto alloc = [&](size_t bytes) {
    size_t r = o;
    o += (bytes + 255) & ~(size_t)255;
    return r;
  };
  int*   deg_in  = (int*)(ws + alloc((size_t)NN * 4));
  float* rs_out  = (float*)(ws + alloc((size_t)NN * 4));
  float* rs_in   = (float*)(ws + alloc((size_t)NN * 4));
  int*   countsS = (int*)(ws + alloc((size_t)SCAN_N * 4));
  int*   countsD = (int*)(ws + alloc((size_t)SCAN_N * 4));
  int*   totS    = (int*)(ws + alloc((size_t)KB * 4));
  int*   totD    = (int*)(ws + alloc((size_t)KB * 4));
  int*   baseS   = (int*)(ws + alloc((size_t)(KB + 1) * 4));
  int*   baseD   = (int*)(ws + alloc((size_t)(KB + 1) * 4));
  int*   cursor_end = (int*)(ws + alloc((size_t)NN * 4));
  u8*    recsS   = (u8*)(ws + alloc((size_t)NE));
  unsigned* recsD = (unsigned*)(ws + alloc((size_t)NE * 4));
  int*   csr_src = (int*)(ws + alloc((size_t)NE * 4));
  u16*   Wt1     = (u16*)(ws + alloc((size_t)DD * DD * 2));
  u16*   Wt2     = (u16*)(ws + alloc((size_t)DD * DD * 2));
  u8*    bufA    = (u8*)(ws + alloc((size_t)NN * DD));      // fp8 row-major L1 input
  u8*    bufB    = (u8*)(ws + alloc((size_t)NN * DD));      // fp8 row-major L2 input
  u16*   aggbuf  = (u16*)(ws + alloc((size_t)NN * DD * 2)); // bf16 row-major agg
  float* pooled  = (float*)(ws + alloc((size_t)NG * DD * 4));
  int*   cnt_part = (int*)(ws + alloc((size_t)GHB * NG * 4));

  // 1: p1 bucket histos + W transposes + gid histo partials + pooled zero
  p1x<<<PB + 128 + GHB + 1, 256, 0, stream>>>(src, dst, countsS, countsD,
                                              W1, W2, Wt1, Wt2, gid, cnt_part, pooled);
  // 2: per-bucket scans
  scanA<<<2 * KB, 256, 0, stream>>>(countsS, countsD, totS, totD);
  // 3: record scatter (+ in-block base scan, publishes baseS/baseD)
  p2x<<<PB, 256, 0, stream>>>(src, dst, countsS, countsD, totS, totD,
                              baseS, baseD, recsS, recsD);
  // 4: src finalize (rs_out + fused x->fp8 conv) ∥ dst finalize (CSR)
  sd_p3x<<<2 * KB, 256, 0, stream>>>(recsS, baseS, rs_out, x, bufA,
                                     recsD, baseD, csr_src, cursor_end, deg_in, rs_in);

  const int gablocks = (NN + 31) / 32;   // 3125
  const int gmblocks = (NN + 127) / 128; // 782

  // 5-6: layer 1
  gather_agg_fp8<<<gablocks, 256, 0, stream>>>((const uint4*)bufA, csr_src, cursor_end, deg_in, aggbuf);
  gemm_mfma_fp8out<<<gmblocks, 256, 0, stream>>>(aggbuf, Wt1, b1, rs_in, rs_out, bufB);
  // 7-8: layer 2
  gather_agg_fp8<<<gablocks, 256, 0, stream>>>((const uint4*)bufB, csr_src, cursor_end, deg_in, aggbuf);
  gemm_mfma_pool<<<gmblocks, 256, 0, stream>>>(aggbuf, Wt2, b2, rs_in, gid, pooled);
  // 9: head
  final_kernel<<<1, 128, 0, stream>>>(pooled, cnt_part, pa, lW, lb, out);
}

// Round 15
// 173.925 us; speedup vs baseline: 1.2139x; 1.1097x over previous
//
#include <hip/hip_runtime.h>
#include <hip/hip_bf16.h>

#define NN 100000
#define NE 1600000
#define DD 128
#define NG 8

#define BSH 8              // 256-node buckets
#define KB 391             // ceil(NN / 256)
#define BMASK 255
#define PB 512             // phase-1/2 blocks
#define CHUNK 3125         // NE / PB exactly
#define SCAN_N (KB * PB)
#define GHB 98             // gid-histo blocks

typedef unsigned short u16;
typedef unsigned char u8;
typedef __attribute__((ext_vector_type(8))) short short8;
typedef __attribute__((ext_vector_type(4))) float f32x4;
typedef __attribute__((ext_vector_type(2))) float f32x2;

static __device__ __forceinline__ u16 f2bf(float f) {
  unsigned u = __float_as_uint(f);
  u += 0x7fffu + ((u >> 16) & 1);
  return (u16)(u >> 16);
}
static __device__ __forceinline__ u8 f2fp8(float f) {
  return (u8)(__builtin_amdgcn_cvt_pk_fp8_f32(f, f, 0, false) & 0xFF);
}

// ---- merged first launch: p1 histograms + W transposes + gid histo + pooled zero ----
__global__ __launch_bounds__(256) void p1x(const int* __restrict__ src,
                                           const int* __restrict__ dst,
                                           int* __restrict__ countsS,
                                           int* __restrict__ countsD,
                                           const float* __restrict__ W1,
                                           const float* __restrict__ W2,
                                           u16* __restrict__ Wt1,
                                           u16* __restrict__ Wt2,
                                           const int* __restrict__ gid,
                                           int* __restrict__ cnt_part,
                                           float* __restrict__ pooled) {
  __shared__ int hs[KB], hd[KB];
  __shared__ int h8[NG];
  int t = threadIdx.x, b = blockIdx.x;
  if (b < PB) {
    for (int i = t; i < KB; i += 256) { hs[i] = 0; hd[i] = 0; }
    __syncthreads();
    int e0 = b * CHUNK;
    for (int i = t; i < CHUNK; i += 256) {
      atomicAdd(&hs[src[e0 + i] >> BSH], 1);
      atomicAdd(&hd[dst[e0 + i] >> BSH], 1);
    }
    __syncthreads();
    for (int i = t; i < KB; i += 256) {
      countsS[i * PB + b] = hs[i];
      countsD[i * PB + b] = hd[i];
    }
  } else if (b < PB + 128) {
    int i = (b - PB) * 256 + t;  // 0..32767
    if (i < DD * DD) {
      int n = i >> 7, k = i & 127;
      Wt1[i] = f2bf(W1[k * DD + n]);
    } else {
      int i2 = i - DD * DD;
      int n = i2 >> 7, k = i2 & 127;
      Wt2[i2] = f2bf(W2[k * DD + n]);
    }
  } else if (b < PB + 128 + GHB) {
    int blk = b - PB - 128;
    if (t < NG) h8[t] = 0;
    __syncthreads();
    for (int i = blk * 256 + t; i < NN; i += GHB * 256)
      atomicAdd(&h8[gid[i]], 1);
    __syncthreads();
    if (t < NG) cnt_part[blk * NG + t] = h8[t];
  } else {
    for (int i = t; i < NG * DD; i += 256) pooled[i] = 0.f;
  }
}

// grid = 2*KB: per-bucket exclusive scan of its PB counts (in place), total out.
__global__ __launch_bounds__(256) void scanA(int* __restrict__ countsS,
                                             int* __restrict__ countsD,
                                             int* __restrict__ totS,
                                             int* __restrict__ totD) {
  __shared__ int data[PB];
  __shared__ int part[256];
  int b = blockIdx.x;
  int isS = (b < KB);
  int k = isS ? b : b - KB;
  int* counts = isS ? countsS : countsD;
  int* tot = isS ? totS : totD;
  int t = threadIdx.x;
  int* c = counts + (size_t)k * PB;
  data[t] = c[t];
  data[t + 256] = c[t + 256];
  __syncthreads();
  int a0 = data[2 * t], a1 = data[2 * t + 1];
  int s = a0 + a1;
  part[t] = s;
  __syncthreads();
  for (int off = 1; off < 256; off <<= 1) {
    int v = (t >= off) ? part[t - off] : 0;
    __syncthreads();
    part[t] += v;
    __syncthreads();
  }
  int ex = part[t] - s;
  data[2 * t] = ex;
  data[2 * t + 1] = ex + a0;
  __syncthreads();
  c[t] = data[t];
  c[t + 256] = data[t + 256];
  if (t == 255) tot[k] = part[255];
}

// exclusive scan of data[0..511] -> out[0..nmax] (out[i] = sum of data[0..i-1])
static __device__ __forceinline__ void exscan512(int t, int* data, int* part,
                                                 int* out, int nmax) {
  __syncthreads();
  int a0 = data[2 * t], a1 = data[2 * t + 1];
  int s = a0 + a1;
  part[t] = s;
  __syncthreads();
  for (int off = 1; off < 256; off <<= 1) {
    int v = (t >= off) ? part[t - off] : 0;
    __syncthreads();
    part[t] += v;
    __syncthreads();
  }
  int ex = part[t] - s;
  if (2 * t <= nmax) out[2 * t] = ex;
  if (2 * t + 1 <= nmax) out[2 * t + 1] = ex + a0;
  __syncthreads();
}

// combined scatter with LDS bucket-sorted staging -> coalesced run writes.
// recsD (u32 CSR records) + recsS (u8 src low bits); block 0 publishes base arrays.
__global__ __launch_bounds__(256) void p2x(const int* __restrict__ src,
                                           const int* __restrict__ dst,
                                           const int* __restrict__ countsS,
                                           const int* __restrict__ countsD,
                                           const int* __restrict__ totS,
                                           const int* __restrict__ totD,
                                           int* __restrict__ baseS,
                                           int* __restrict__ baseD,
                                           u8* __restrict__ recsS,
                                           unsigned* __restrict__ recsD) {
  __shared__ int data[512];
  __shared__ int part[256];
  __shared__ int bS[KB + 1], bD[KB + 1];      // global bucket bases
  __shared__ int gS[KB], gD[KB];              // this block's run start per bucket
  __shared__ int lsS[KB + 1], lsD[KB + 1];    // local exclusive starts
  __shared__ int lcS[KB], lcD[KB];            // local cursors
  __shared__ unsigned stD[CHUNK];             // staged D records (bucket-major)
  __shared__ u16 bkD[CHUNK];
  __shared__ u8 stS[CHUNK];                   // staged S records (bucket-major)
  __shared__ u16 bkS[CHUNK];
  int t = threadIdx.x, blk = blockIdx.x;

  // scan 1: totS -> bS
  data[t] = (t < KB) ? totS[t] : 0;
  data[t + 256] = (t + 256 < KB) ? totS[t + 256] : 0;
  exscan512(t, data, part, bS, KB);
  // scan 2: totD -> bD
  data[t] = (t < KB) ? totD[t] : 0;
  data[t + 256] = (t + 256 < KB) ? totD[t + 256] : 0;
  exscan512(t, data, part, bD, KB);

  if (blk == 0) {
    for (int i = t; i <= KB; i += 256) {
      baseS[i] = bS[i];
      baseD[i] = bD[i];
    }
  }

  // local counts + global run starts (S)
  for (int k = t; k < 512; k += 256) {
    int cnt = 0;
    if (k < KB) {
      int pref = countsS[k * PB + blk];
      int nxt = (blk < PB - 1) ? countsS[k * PB + blk + 1] : totS[k];
      cnt = nxt - pref;
      gS[k] = bS[k] + pref;
    }
    data[k] = cnt;
  }
  exscan512(t, data, part, lsS, KB);
  // local counts + global run starts (D)
  for (int k = t; k < 512; k += 256) {
    int cnt = 0;
    if (k < KB) {
      int pref = countsD[k * PB + blk];
      int nxt = (blk < PB - 1) ? countsD[k * PB + blk + 1] : totD[k];
      cnt = nxt - pref;
      gD[k] = bD[k] + pref;
    }
    data[k] = cnt;
  }
  exscan512(t, data, part, lsD, KB);

  for (int k = t; k < KB; k += 256) {
    lcS[k] = lsS[k];
    lcD[k] = lsD[k];
  }
  __syncthreads();

  // phase B: stage bucket-major into LDS
  int e0 = blk * CHUNK;
  for (int i = t; i < CHUNK; i += 256) {
    int s = src[e0 + i];
    int d = dst[e0 + i];
    int ks = s >> BSH;
    int kd = d >> BSH;
    int ps = atomicAdd(&lcS[ks], 1);
    stS[ps] = (u8)(s & BMASK);
    bkS[ps] = (u16)ks;
    int pd = atomicAdd(&lcD[kd], 1);
    stD[pd] = (unsigned)s | ((unsigned)(d & BMASK) << 17);
    bkD[pd] = (u16)kd;
  }
  __syncthreads();

  // phase C: coalesced run writes to global
  for (int i = t; i < CHUNK; i += 256) {
    int kd = bkD[i];
    recsD[gD[kd] + (i - lsD[kd])] = stD[i];
    int ks = bkS[i];
    recsS[gS[ks] + (i - lsS[ks])] = stS[i];
  }
}

// merged grid 2*KB: blocks [0,KB) = src histogram -> rs_out AND x->fp8 scaled conv;
// blocks [KB,2KB) = dst: cursor_end + csr scatter + deg_in/rs_in.
__global__ __launch_bounds__(256) void sd_p3x(const u8* __restrict__ recsS,
                                              const int* __restrict__ baseS,
                                              float* __restrict__ rs_out,
                                              const float* __restrict__ x,
                                              u8* __restrict__ bufA,
                                              const unsigned* __restrict__ recsD,
                                              const int* __restrict__ baseD,
                                              int* __restrict__ csr_src,
                                              int* __restrict__ cursor_end,
                                              int* __restrict__ deg_in,
                                              float* __restrict__ rs_in) {
  __shared__ int hist[256];
  __shared__ int part[256];
  __shared__ float rsl[256];
  int t = threadIdx.x;
  if (blockIdx.x < KB) {
    int k = blockIdx.x;
    int rbeg = baseS[k];
    int rend = baseS[k + 1];
    hist[t] = 0;
    __syncthreads();
    for (int i = rbeg + t; i < rend; i += 256) atomicAdd(&hist[recsS[i]], 1);
    __syncthreads();
    int nbase = k << BSH;
    int n = nbase + t;
    float rv = rsqrtf(fmaxf((float)hist[t], 1.f));
    rsl[t] = rv;
    if (n < NN) rs_out[n] = rv;
    __syncthreads();
    // fused conv: x[node] * rs -> fp8 row-major, 256 nodes x 16 chunks of 8
    for (int i = t; i < 256 * 16; i += 256) {
      int row = i >> 4, c = i & 15;
      int node = nbase + row;
      if (node >= NN) break;   // rows processed in order; tail bucket only
      float w = rsl[row];
      const float4* p = (const float4*)(x + (size_t)node * DD + c * 8);
      float4 a = p[0], b = p[1];
      int lo = 0, hi = 0;
      lo = __builtin_amdgcn_cvt_pk_fp8_f32(a.x * w, a.y * w, lo, false);
      lo = __builtin_amdgcn_cvt_pk_fp8_f32(a.z * w, a.w * w, lo, true);
      hi = __builtin_amdgcn_cvt_pk_fp8_f32(b.x * w, b.y * w, hi, false);
      hi = __builtin_amdgcn_cvt_pk_fp8_f32(b.z * w, b.w * w, hi, true);
      *(uint2*)(bufA + (size_t)node * DD + c * 8) = make_uint2((unsigned)lo, (unsigned)hi);
    }
  } else {
    int k = blockIdx.x - KB;
    int rbeg = baseD[k];
    int rend = baseD[k + 1];
    hist[t] = 0;
    __syncthreads();
    for (int i = rbeg + t; i < rend; i += 256) atomicAdd(&hist[recsD[i] >> 17], 1);
    __syncthreads();
    int h = hist[t];
    part[t] = h;
    __syncthreads();
    for (int off = 1; off < 256; off <<= 1) {
      int v = (t >= off) ? part[t - off] : 0;
      __syncthreads();
      part[t] += v;
      __syncthreads();
    }
    int run = rbeg + part[t] - h;   // exclusive
    int n = (k << BSH) + t;
    if (n < NN) {
      cursor_end[n] = run + h;
      deg_in[n] = h;
      rs_in[n] = rsqrtf(fmaxf((float)h, 1.f));
    }
    hist[t] = run;
    __syncthreads();
    for (int i = rbeg + t; i < rend; i += 256) {
      unsigned r = recsD[i];
      int pos = atomicAdd(&hist[r >> 17], 1);
      csr_src[pos] = (int)(r & 0x1FFFF);
    }
  }
}

// One 8-lane group per dst node; lane q covers fp8 elems 16q..16q+15 (16B).
// 4-deep unroll, scalar idx loads — VGPR 44, occupancy ~44%.
__global__ __launch_bounds__(256) void gather_agg_fp8(
    const uint4* __restrict__ Hv, const int* __restrict__ csr_src,
    const int* __restrict__ cursor_end, const int* __restrict__ deg_in,
    u16* __restrict__ agg) {
  int node = blockIdx.x * 32 + (threadIdx.x >> 3);
  if (node >= NN) return;
  int q = threadIdx.x & 7;
  int end = cursor_end[node];
  int j = end - deg_in[node];
  float acc[16];
#pragma unroll
  for (int i = 0; i < 16; ++i) acc[i] = 0.f;
#define ACCV(v) { f32x2 t_;                                                        \
  t_ = __builtin_amdgcn_cvt_pk_f32_fp8((int)(v).x, false); acc[0] += t_.x;  acc[1] += t_.y;  \
  t_ = __builtin_amdgcn_cvt_pk_f32_fp8((int)(v).x, true);  acc[2] += t_.x;  acc[3] += t_.y;  \
  t_ = __builtin_amdgcn_cvt_pk_f32_fp8((int)(v).y, false); acc[4] += t_.x;  acc[5] += t_.y;  \
  t_ = __builtin_amdgcn_cvt_pk_f32_fp8((int)(v).y, true);  acc[6] += t_.x;  acc[7] += t_.y;  \
  t_ = __builtin_amdgcn_cvt_pk_f32_fp8((int)(v).z, false); acc[8] += t_.x;  acc[9] += t_.y;  \
  t_ = __builtin_amdgcn_cvt_pk_f32_fp8((int)(v).z, true);  acc[10] += t_.x; acc[11] += t_.y; \
  t_ = __builtin_amdgcn_cvt_pk_f32_fp8((int)(v).w, false); acc[12] += t_.x; acc[13] += t_.y; \
  t_ = __builtin_amdgcn_cvt_pk_f32_fp8((int)(v).w, true);  acc[14] += t_.x; acc[15] += t_.y; }
  for (; j + 4 <= end; j += 4) {
    int s0 = csr_src[j + 0];
    int s1 = csr_src[j + 1];
    int s2 = csr_src[j + 2];
    int s3 = csr_src[j + 3];
    uint4 v0 = Hv[(size_t)s0 * 8 + q];
    uint4 v1 = Hv[(size_t)s1 * 8 + q];
    uint4 v2 = Hv[(size_t)s2 * 8 + q];
    uint4 v3 = Hv[(size_t)s3 * 8 + q];
    ACCV(v0) ACCV(v1) ACCV(v2) ACCV(v3)
  }
  for (; j < end; ++j) {
    uint4 v = Hv[(size_t)csr_src[j] * 8 + q];
    ACCV(v)
  }
#undef ACCV
  uint4 o0, o1;
  o0.x = (unsigned)f2bf(acc[0])  | ((unsigned)f2bf(acc[1])  << 16);
  o0.y = (unsigned)f2bf(acc[2])  | ((unsigned)f2bf(acc[3])  << 16);
  o0.z = (unsigned)f2bf(acc[4])  | ((unsigned)f2bf(acc[5])  << 16);
  o0.w = (unsigned)f2bf(acc[6])  | ((unsigned)f2bf(acc[7])  << 16);
  o1.x = (unsigned)f2bf(acc[8])  | ((unsigned)f2bf(acc[9])  << 16);
  o1.y = (unsigned)f2bf(acc[10]) | ((unsigned)f2bf(acc[11]) << 16);
  o1.z = (unsigned)f2bf(acc[12]) | ((unsigned)f2bf(acc[13]) << 16);
  o1.w = (unsigned)f2bf(acc[14]) | ((unsigned)f2bf(acc[15]) << 16);
  u16* op = agg + (size_t)node * DD + q * 16;
  *(uint4*)op = o0;
  *(uint4*)(op + 8) = o1;
}

// ---- LDS-staged GEMM core ----
#define GEMM_PRE                                                              \
  __shared__ uint4 Wl4[2048]; /* 32 KB */                                     \
  int tid = threadIdx.x;                                                      \
  {                                                                           \
    const uint4* Wg4 = (const uint4*)Wt;                                      \
    for (int i = tid; i < 2048; i += 256) {                                   \
      int row = i >> 4, c = i & 15;                                           \
      Wl4[(row << 4) | (c ^ (row & 15))] = Wg4[i];                            \
    }                                                                         \
  }                                                                           \
  int wid = tid >> 6;                                                         \
  int lane = tid & 63;                                                        \
  int l15 = lane & 15;                                                        \
  int kg = lane >> 4;                                                         \
  int rowbase = blockIdx.x * 128 + wid * 32;                                  \
  f32x4 acc[2][8];                                                            \
  short8 a[2][4];                                                             \
  _Pragma("unroll")                                                           \
  for (int t = 0; t < 2; ++t) {                                               \
    int arow = rowbase + t * 16 + l15;                                        \
    bool ok = arow < NN;                                                      \
    const u16* aptr = Ab + (size_t)arow * DD + kg * 8;                        \
    _Pragma("unroll")                                                         \
    for (int kt = 0; kt < 4; ++kt) {                                          \
      a[t][kt] = ok ? *(const short8*)(aptr + kt * 32)                        \
                    : (short8){0, 0, 0, 0, 0, 0, 0, 0};                       \
      acc[0][kt] = (f32x4){0.f, 0.f, 0.f, 0.f};                               \
      acc[0][kt + 4] = (f32x4){0.f, 0.f, 0.f, 0.f};                           \
      acc[1][kt] = (f32x4){0.f, 0.f, 0.f, 0.f};                               \
      acc[1][kt + 4] = (f32x4){0.f, 0.f, 0.f, 0.f};                           \
    }                                                                         \
  }                                                                           \
  __syncthreads();                                                            \
  _Pragma("unroll")                                                           \
  for (int n = 0; n < 8; ++n) {                                               \
    _Pragma("unroll")                                                         \
    for (int kt = 0; kt < 4; ++kt) {                                          \
      short8 b = *(const short8*)(Wl4 + (((n * 16 + l15) << 4) |              \
                                         ((kg + kt * 4) ^ l15)));             \
      acc[0][n] = __builtin_amdgcn_mfma_f32_16x16x32_bf16(a[0][kt], b, acc[0][n], 0, 0, 0); \
      acc[1][n] = __builtin_amdgcn_mfma_f32_16x16x32_bf16(a[1][kt], b, acc[1][n], 0, 0, 0); \
    }                                                                         \
  }

// C = fp8( relu((A@W)*rs + bias) * post ), row-major byte out.
__global__ __launch_bounds__(256) void gemm_mfma_fp8out(
    const u16* __restrict__ Ab, const u16* __restrict__ Wt,
    const float* __restrict__ bias, const float* __restrict__ rs,
    const float* __restrict__ post, u8* __restrict__ Cb) {
  GEMM_PRE
#pragma unroll
  for (int t = 0; t < 2; ++t) {
    int crow0 = rowbase + t * 16 + kg * 4;
#pragma unroll
    for (int j = 0; j < 4; ++j) {
      int r = crow0 + j;
      if (r < NN) {
        float s = rs[r];
        float ps = post[r];
#pragma unroll
        for (int n = 0; n < 8; ++n) {
          float v = fmaxf(acc[t][n][j] * s + bias[n * 16 + l15], 0.f) * ps;
          Cb[(size_t)r * DD + n * 16 + l15] = f2fp8(v);
        }
      }
    }
  }
}

// Layer-2 GEMM with pooling fused into the epilogue: no feature output.
__global__ __launch_bounds__(256) void gemm_mfma_pool(
    const u16* __restrict__ Ab, const u16* __restrict__ Wt,
    const float* __restrict__ bias, const float* __restrict__ rs,
    const int* __restrict__ gid, float* __restrict__ pooled) {
  __shared__ float pl[NG * DD];  // 4 KB
  for (int i = threadIdx.x; i < NG * DD; i += 256) pl[i] = 0.f;
  GEMM_PRE
  float pacc[8];
#pragma unroll
  for (int n = 0; n < 8; ++n) pacc[n] = 0.f;
  int curg = -1;
#pragma unroll
  for (int t = 0; t < 2; ++t) {
    int crow0 = rowbase + t * 16 + kg * 4;
#pragma unroll
    for (int j = 0; j < 4; ++j) {
      int r = crow0 + j;
      if (r < NN) {
        int g = gid[r];
        if (g != curg) {
          if (curg >= 0) {
#pragma unroll
            for (int n = 0; n < 8; ++n) {
              atomicAdd(&pl[curg * DD + n * 16 + l15], pacc[n]);
              pacc[n] = 0.f;
            }
          }
          curg = g;
        }
        float s = rs[r];
#pragma unroll
        for (int n = 0; n < 8; ++n)
          pacc[n] += fmaxf(acc[t][n][j] * s + bias[n * 16 + l15], 0.f);
      }
    }
  }
  if (curg >= 0) {
#pragma unroll
    for (int n = 0; n < 8; ++n)
      atomicAdd(&pl[curg * DD + n * 16 + l15], pacc[n]);
  }
  __syncthreads();
  int rlo = blockIdx.x * 128;
  int rhi = rlo + 127;
  if (rhi >= NN) rhi = NN - 1;
  int gmin = gid[rlo];
  int gmax = gid[rhi];
  int span = (gmax - gmin + 1) * DD;
  for (int i = tid; i < span; i += 256) {
    float v = pl[gmin * DD + i];
    if (v != 0.f) atomicAdd(&pooled[gmin * DD + i], v);
  }
}

__global__ __launch_bounds__(128) void final_kernel(const float* __restrict__ pooled,
                                                    const int* __restrict__ cnt_part,
                                                    const float* __restrict__ prelu_a,
                                                    const float* __restrict__ linW,
                                                    const float* __restrict__ linb,
                                                    float* __restrict__ out) {
  int t = threadIdx.x;  // 128
  __shared__ float red[2];
  __shared__ int cntl[NG];
  if (t < NG) {
    int s = 0;
    for (int b = 0; b < GHB; ++b) s += cnt_part[b * NG + t];
    cntl[t] = s;
  }
  __syncthreads();
  float w = linW[t];
  float alpha = prelu_a[0];
  float lb = linb[0];
  for (int g = 0; g < NG; ++g) {
    float v = pooled[g * DD + t] / fmaxf((float)cntl[g], 1.f);
    v = v > 0.f ? v : alpha * v;
    float p = v * w;
#pragma unroll
    for (int off = 32; off >= 1; off >>= 1) p += __shfl_down(p, off, 64);
    if ((t & 63) == 0) red[t >> 6] = p;
    __syncthreads();
    if (t == 0) {
      float s = red[0] + red[1] + lb;
      out[g] = 1.f / (1.f + expf(-s));
    }
    __syncthreads();
  }
}

extern "C" void kernel_launch(void* const* d_in, const int* in_sizes, int n_in,
                              void* d_out, int out_size, void* d_ws, size_t ws_size,
                              hipStream_t stream) {
  const float* x   = (const float*)d_in[0];
  const int*   src = (const int*)d_in[1];
  const int*   dst = (const int*)d_in[2];
  const int*   gid = (const int*)d_in[3];
  const float* W1  = (const float*)d_in[4];
  const float* b1  = (const float*)d_in[5];
  const float* W2  = (const float*)d_in[6];
  const float* b2  = (const float*)d_in[7];
  const float* pa  = (const float*)d_in[8];
  const float* lW  = (const float*)d_in[9];
  const float* lb  = (const float*)d_in[10];
  float* out = (float*)d_out;

  char* ws = (char*)d_ws;
  size_t o = 0;
  auto alloc = [&](size_t bytes) {
    size_t r = o;
    o += (bytes + 255) & ~(size_t)255;
    return r;
  };
  int*   deg_in  = (int*)(ws + alloc((size_t)NN * 4));
  float* rs_out  = (float*)(ws + alloc((size_t)NN * 4));
  float* rs_in   = (float*)(ws + alloc((size_t)NN * 4));
  int*   countsS = (int*)(ws + alloc((size_t)SCAN_N * 4));
  int*   countsD = (int*)(ws + alloc((size_t)SCAN_N * 4));
  int*   totS    = (int*)(ws + alloc((size_t)KB * 4));
  int*   totD    = (int*)(ws + alloc((size_t)KB * 4));
  int*   baseS   = (int*)(ws + alloc((size_t)(KB + 1) * 4));
  int*   baseD   = (int*)(ws + alloc((size_t)(KB + 1) * 4));
  int*   cursor_end = (int*)(ws + alloc((size_t)NN * 4));
  u8*    recsS   = (u8*)(ws + alloc((size_t)NE));
  unsigned* recsD = (unsigned*)(ws + alloc((size_t)NE * 4));
  int*   csr_src = (int*)(ws + alloc((size_t)NE * 4));
  u16*   Wt1     = (u16*)(ws + alloc((size_t)DD * DD * 2));
  u16*   Wt2     = (u16*)(ws + alloc((size_t)DD * DD * 2));
  u8*    bufA    = (u8*)(ws + alloc((size_t)NN * DD));      // fp8 row-major L1 input
  u8*    bufB    = (u8*)(ws + alloc((size_t)NN * DD));      // fp8 row-major L2 input
  u16*   aggbuf  = (u16*)(ws + alloc((size_t)NN * DD * 2)); // bf16 row-major agg
  float* pooled  = (float*)(ws + alloc((size_t)NG * DD * 4));
  int*   cnt_part = (int*)(ws + alloc((size_t)GHB * NG * 4));

  // 1: p1 bucket histos + W transposes + gid histo partials + pooled zero
  p1x<<<PB + 128 + GHB + 1, 256, 0, stream>>>(src, dst, countsS, countsD,
                                              W1, W2, Wt1, Wt2, gid, cnt_part, pooled);
  // 2: per-bucket scans
  scanA<<<2 * KB, 256, 0, stream>>>(countsS, countsD, totS, totD);
  // 3: record scatter with LDS bucket-sorted staging (publishes baseS/baseD)
  p2x<<<PB, 256, 0, stream>>>(src, dst, countsS, countsD, totS, totD,
                              baseS, baseD, recsS, recsD);
  // 4: src finalize (rs_out + fused x->fp8 conv) ∥ dst finalize (CSR)
  sd_p3x<<<2 * KB, 256, 0, stream>>>(recsS, baseS, rs_out, x, bufA,
                                     recsD, baseD, csr_src, cursor_end, deg_in, rs_in);

  const int gablocks = (NN + 31) / 32;   // 3125
  const int gmblocks = (NN + 127) / 128; // 782

  // 5-6: layer 1
  gather_agg_fp8<<<gablocks, 256, 0, stream>>>((const uint4*)bufA, csr_src, cursor_end, deg_in, aggbuf);
  gemm_mfma_fp8out<<<gmblocks, 256, 0, stream>>>(aggbuf, Wt1, b1, rs_in, rs_out, bufB);
  // 7-8: layer 2
  gather_agg_fp8<<<gablocks, 256, 0, stream>>>((const uint4*)bufB, csr_src, cursor_end, deg_in, aggbuf);
  gemm_mfma_pool<<<gmblocks, 256, 0, stream>>>(aggbuf, Wt2, b2, rs_in, gid, pooled);
  // 9: head
  final_kernel<<<1, 128, 0, stream>>>(pooled, cnt_part, pa, lW, lb, out);
}